// Round 1
// baseline (1187.392 us; speedup 1.0000x reference)
//
#include <hip/hip_runtime.h>
#include <hip/hip_bf16.h>

// Problem constants (match reference)
#define DIMT 300      // TERM_DIM
#define DPAD 320      // padded to 32
#define NRELS 40
#define RELD 5
#define TILE_M 128    // elements per chunk/workgroup (512 threads, 8 waves)
#define MAX_CHUNKS 8192   // desc array capacity (layout-compatible with prior ws)
#define GEMM_GRID 4096    // >= 40 + ceil(500000/128) = 3947

typedef __attribute__((ext_vector_type(8))) short bf16x8;
typedef __attribute__((ext_vector_type(4))) float f32x4;

// ---------------- workspace layout (ints) ----------------
#define DESC_OFF 256
#define SORTED_OFF (DESC_OFF + 3*MAX_CHUNKS)
#define MT_OFF_BYTES(B) ((((size_t)(SORTED_OFF + (B)) * 4) + 255) & ~(size_t)255)

__global__ void k_init(int* cnt) {
    int t = threadIdx.x;
    if (t < 64) cnt[t] = 0;
    if (t < 64) cnt[64 + t] = 0;
    if (t == 0) cnt[128] = 0;
}

__global__ void k_hist(const int* __restrict__ rels, int n, int* cnt) {
    __shared__ int l[NRELS];
    int t = threadIdx.x;
    if (t < NRELS) l[t] = 0;
    __syncthreads();
    int b = blockIdx.x * 256 + t;
    if (b < n) atomicAdd(&l[rels[b]], 1);
    __syncthreads();
    if (t < NRELS && l[t]) atomicAdd(&cnt[t], l[t]);
}

__global__ void k_scan(const int* __restrict__ cnt, int* cursor, int* n_chunks,
                       int* desc_rel, int* desc_start, int* desc_end) {
    __shared__ int offs[NRELS + 1];
    __shared__ int coff[NRELS + 1];
    if (threadIdx.x == 0) {
        int s = 0, c = 0;
        for (int r = 0; r < NRELS; r++) {
            offs[r] = s; s += cnt[r];
            coff[r] = c; c += (cnt[r] + TILE_M - 1) / TILE_M;
        }
        offs[NRELS] = s; coff[NRELS] = c;
        *n_chunks = c;
    }
    __syncthreads();
    if (threadIdx.x < NRELS) cursor[threadIdx.x] = offs[threadIdx.x];
    for (int r = 0; r < NRELS; r++) {
        int nch = (cnt[r] + TILE_M - 1) / TILE_M;
        int cend = offs[r] + cnt[r];
        for (int c = threadIdx.x; c < nch; c += 256) {
            int st = offs[r] + c * TILE_M;
            desc_rel[coff[r] + c] = r;
            desc_start[coff[r] + c] = st;
            desc_end[coff[r] + c] = min(st + TILE_M, cend);
        }
    }
}

__global__ void k_scatter(const int* __restrict__ rels, int n, int* cursor,
                          int* __restrict__ sorted) {
    __shared__ int l[NRELS];
    __shared__ int base[NRELS];
    int t = threadIdx.x;
    if (t < NRELS) l[t] = 0;
    __syncthreads();
    int b = blockIdx.x * 256 + t;
    int r = -1, loc = 0;
    if (b < n) { r = rels[b]; loc = atomicAdd(&l[r], 1); }
    __syncthreads();
    if (t < NRELS && l[t]) base[t] = atomicAdd(&cursor[t], l[t]);
    __syncthreads();
    if (b < n) sorted[base[r] + loc] = b;
}

// Mt[r][n][.] = sum_i rel_table[r,i] * assoc[i][j][n], zero-padded to 320x320,
// with the j dimension stored XOR-swizzled per row: the 8-element j-chunk jc
// lands at chunk position (jc ^ (n & 7)). This makes the k_gemm panel staging
// a fully linear global_load_lds copy while keeping ds_read_b128 reads spread
// across banks (row stride 640 B would otherwise be a 16-way conflict).
__global__ void k_build_mt(const float* __restrict__ rel_table,
                           const float* __restrict__ assoc,
                           __hip_bfloat16* __restrict__ Mt) {
    int r = blockIdx.x / 100;
    int t6 = blockIdx.x % 100;
    int tn = (t6 / 10) * 32, tj = (t6 % 10) * 32;
    __shared__ float tile[32][33];
    __shared__ float rw[RELD];
    if (threadIdx.x < RELD) rw[threadIdx.x] = rel_table[r * RELD + threadIdx.x];
    __syncthreads();
    for (int e = threadIdx.x; e < 1024; e += 256) {
        int jl = e >> 5, nl = e & 31;
        int j = tj + jl, n = tn + nl;
        float v = 0.f;
        if (j < DIMT && n < DIMT) {
            #pragma unroll
            for (int i = 0; i < RELD; i++) v += rw[i] * assoc[(i * DIMT + j) * DIMT + n];
        }
        tile[jl][nl] = v;
    }
    __syncthreads();
    for (int e = threadIdx.x; e < 1024; e += 256) {
        int nl = e >> 5, jl = e & 31;
        int n = tn + nl, j = tj + jl;
        int sj = (((j >> 3) ^ (n & 7)) << 3) | (j & 7);   // XOR-swizzled j position
        Mt[((size_t)r * DPAD + n) * DPAD + sj] = __float2bfloat16(tile[jl][nl]);
    }
}

// async 16B global -> LDS (direct-to-shared DMA, no VGPR round trip)
__device__ inline void async_g2l16(const void* g, void* l) {
    __builtin_amdgcn_global_load_lds(
        (const __attribute__((address_space(1))) unsigned int*)g,
        (__attribute__((address_space(3))) unsigned int*)l, 16, 0, 0);
}

// Grouped GEMM, N-panel-outer / K-inner with on-the-fly tR contraction:
// per chunk of <=128 rows of one relation, for each 32-col N-panel:
//   acc[m, n-panel] = sum_j tL[m][j] * M[j][n]     (20 MFMA / wave / panel)
//   en[m]          += sum_{n in panel} acc * tR[m][n]
// acc is only 8 f32/lane (vs 80 for the full X tile) -> register pressure
// drops enough to run 512-thread blocks at 3 blocks/CU (24 waves target).
// B panel = 32 contiguous (pre-swizzled) Mt rows = one linear 20 KB
// global_load_lds copy, double-buffered.
__global__ __launch_bounds__(512, 6) void k_gemm(
    const int* __restrict__ sorted, const int* __restrict__ desc_rel,
    const int* __restrict__ desc_start, const int* __restrict__ desc_end,
    const int* __restrict__ n_chunks,
    const int* __restrict__ terms_L, const int* __restrict__ terms_R,
    const float* __restrict__ term_table, const __hip_bfloat16* __restrict__ Mt,
    float* __restrict__ out) {
    int cid = blockIdx.x;
    if (cid >= *n_chunks) return;
    int rel = desc_rel[cid];
    int start = desc_start[cid];
    int tm = desc_end[cid] - start;

    // B panel buffers: [buf][n_local*320 + j_swizzled] bf16, 2 x 20 KB
    __shared__ __align__(16) __hip_bfloat16 Blds[2][32 * DPAD];
    __shared__ int elds[TILE_M];

    int t = threadIdx.x;
    if (t < TILE_M) elds[t] = (t < tm) ? sorted[start + t] : -1;

    int wave = t >> 6, lane = t & 63;
    int quad = lane >> 4, l16 = lane & 15;

    const __hip_bfloat16* Mtr = Mt + (size_t)rel * DPAD * DPAD;

    // ---- panel staging: 20480 B = 1280 x 16B chunks over 512 threads ----
    // LDS dest is wave-uniform base + lane*16 (linear) as global_load_lds
    // requires; the bank swizzle is pre-baked into Mt's global layout.
    auto stage = [&](int np, int buf) {
        const char* gb = (const char*)Mtr + (size_t)np * (32 * DPAD * 2);
        char* lb = (char*)&Blds[buf][0];
        async_g2l16(gb + t * 16, lb + t * 16);
        async_g2l16(gb + (t + 512) * 16, lb + (t + 512) * 16);
        if (t < 256)  // waves 0-3 entirely: wave-uniform guard
            async_g2l16(gb + (t + 1024) * 16, lb + (t + 1024) * 16);
    };

    __syncthreads();  // elds visible

    // kick off both panel prefetches before the (long-latency) A gather
    stage(0, 0);
    stage(1, 1);

    // ---- A preload: lane holds row elds[wave*16+l16], k-octet quad*8, all kc ----
    int arow = wave * 16 + l16;
    int ae = elds[arow];
    const float* arp = (ae >= 0) ? (term_table + (size_t)terms_L[ae] * DIMT) : nullptr;
    bf16x8 afrag[10];
    #pragma unroll
    for (int kc = 0; kc < 10; kc++) {
        int kb = kc * 32 + quad * 8;
        float v[8];
        if (arp && kb + 8 <= DIMT) {
            float4 p0 = *(const float4*)(arp + kb);
            float4 p1 = *(const float4*)(arp + kb + 4);
            v[0] = p0.x; v[1] = p0.y; v[2] = p0.z; v[3] = p0.w;
            v[4] = p1.x; v[5] = p1.y; v[6] = p1.z; v[7] = p1.w;
        } else if (arp) {
            #pragma unroll
            for (int j = 0; j < 8; j++) v[j] = (kb + j < DIMT) ? arp[kb + j] : 0.f;
        } else {
            #pragma unroll
            for (int j = 0; j < 8; j++) v[j] = 0.f;
        }
        union { bf16x8 v8; __hip_bfloat16 h[8]; } u;
        #pragma unroll
        for (int j = 0; j < 8; j++) u.h[j] = __float2bfloat16(v[j]);
        afrag[kc] = u.v8;
    }

    // tR row offsets for the 4 output rows this lane owns (C-layout rows)
    int troff[4];
    #pragma unroll
    for (int reg = 0; reg < 4; reg++) {
        int er = elds[wave * 16 + quad * 4 + reg];
        troff[reg] = (er >= 0) ? (int)((size_t)terms_R[er] * DIMT) : -1;
    }

    float en[4] = {0.f, 0.f, 0.f, 0.f};

    __syncthreads();  // drains stage(0)+stage(1) + everyone's A loads

    int sw = (l16 & 7) << 4;  // read-side XOR matching Mt's baked swizzle
    for (int np = 0; np < 10; np++) {
        int cur = np & 1;
        if (np >= 1 && np <= 8) stage(np + 1, cur ^ 1);  // buf^1 free since barrier
        const char* bb = (const char*)&Blds[cur][0];
        f32x4 acc0 = {0.f, 0.f, 0.f, 0.f};
        f32x4 acc1 = {0.f, 0.f, 0.f, 0.f};
        #pragma unroll
        for (int kc = 0; kc < 10; kc++) {
            int jcb = (kc * 4 + quad) << 4;
            bf16x8 b0 = *(const bf16x8*)(bb + l16 * (DPAD * 2) + (jcb ^ sw));
            bf16x8 b1 = *(const bf16x8*)(bb + (16 + l16) * (DPAD * 2) + (jcb ^ sw));
            acc0 = __builtin_amdgcn_mfma_f32_16x16x32_bf16(afrag[kc], b0, acc0, 0, 0, 0);
            acc1 = __builtin_amdgcn_mfma_f32_16x16x32_bf16(afrag[kc], b1, acc1, 0, 0, 0);
        }
        // contract this panel with tR immediately (cols c0 = np*32+l16, c1 = c0+16)
        int c0 = np * 32 + l16, c1 = c0 + 16;
        #pragma unroll
        for (int reg = 0; reg < 4; reg++) {
            if (troff[reg] >= 0) {
                float t0 = (c0 < DIMT) ? term_table[troff[reg] + c0] : 0.f;
                float t1 = (c1 < DIMT) ? term_table[troff[reg] + c1] : 0.f;
                en[reg] += acc0[reg] * t0 + acc1[reg] * t1;
            }
        }
        __syncthreads();  // all waves done reading buf[cur]; prefetch had full panel in flight
    }

    // Final reduce over the 16 l16-lanes (columns) per owned row.
    #pragma unroll
    for (int reg = 0; reg < 4; reg++) {
        float s = en[reg];
        s += __shfl_xor(s, 1);
        s += __shfl_xor(s, 2);
        s += __shfl_xor(s, 4);
        s += __shfl_xor(s, 8);
        if (l16 == 0) {
            int e = elds[wave * 16 + quad * 4 + reg];
            if (e >= 0) out[e] = s;
        }
    }
}

extern "C" void kernel_launch(void* const* d_in, const int* in_sizes, int n_in,
                              void* d_out, int out_size, void* d_ws, size_t ws_size,
                              hipStream_t stream) {
    const int*   rels       = (const int*)d_in[0];
    const int*   terms_L    = (const int*)d_in[1];
    const int*   terms_R    = (const int*)d_in[2];
    const float* term_table = (const float*)d_in[3];
    const float* rel_table  = (const float*)d_in[4];
    const float* assoc      = (const float*)d_in[5];
    float* out = (float*)d_out;
    int B = in_sizes[0];

    int* wsi        = (int*)d_ws;
    int* cnt        = wsi;
    int* cursor     = wsi + 64;
    int* n_chunks   = wsi + 128;
    int* desc_rel   = wsi + DESC_OFF;
    int* desc_start = desc_rel + MAX_CHUNKS;
    int* desc_end   = desc_start + MAX_CHUNKS;
    int* sorted     = wsi + SORTED_OFF;
    __hip_bfloat16* Mt = (__hip_bfloat16*)((char*)d_ws + MT_OFF_BYTES(B));

    int nb = (B + 255) / 256;
    k_init<<<1, 128, 0, stream>>>(cnt);
    k_hist<<<nb, 256, 0, stream>>>(rels, B, cnt);
    k_scan<<<1, 256, 0, stream>>>(cnt, cursor, n_chunks, desc_rel, desc_start, desc_end);
    k_scatter<<<nb, 256, 0, stream>>>(rels, B, cursor, sorted);
    k_build_mt<<<NRELS * 100, 256, 0, stream>>>(rel_table, assoc, Mt);
    k_gemm<<<GEMM_GRID, 512, 0, stream>>>(sorted, desc_rel, desc_start, desc_end,
                                          n_chunks, terms_L, terms_R, term_table, Mt, out);
}